// Round 13
// baseline (197.213 us; speedup 1.0000x reference)
//
#include <hip/hip_runtime.h>
#include <math.h>

#define N_NODES 50000
#define N_EDGES 800000
#define NFEAT 256
#define NHID 64
#define NCLASS 40
#define NPB 16            // nodes per fine bucket
#define NB  3125          // fine buckets = 50000 / 16
#define CAP 512           // slots per fine bucket (mean 256, sigma 16)
#define NC 98             // coarse buckets: dst>>9 (512 nodes each)
#define CAPC 16384        // slots per coarse bucket (mean 8163, sigma 90)
#define BIN_EPB 8192      // edges per pass-A block
#define NBIN 98           // ceil(800000 / 8192)
#define NGEMM 782         // ceil(50000 / 64)
#define NW2 48            // padded class cols (3 MFMA col-tiles)
#define ACC1S 68          // spmm1b acc row stride (pad vs 16-way xpose conflict)

typedef __attribute__((ext_vector_type(8))) short bf16x8;
typedef __attribute__((ext_vector_type(4))) float f32x4;

__device__ __forceinline__ ushort f2bf(float f) {
    unsigned u = __float_as_uint(f);
    u += 0x7FFF + ((u >> 16) & 1);          // round-to-nearest-even
    return (ushort)(u >> 16);
}
__device__ __forceinline__ float bf2f(ushort us) {
    return __uint_as_float(((unsigned)us) << 16);
}

// -------- prep: W1,W2 -> bf16 fragment-ordered tables --------
__global__ __launch_bounds__(256) void k_prep(const float* __restrict__ W1,
                                              const float* __restrict__ W2,
                                              ushort* __restrict__ W1f,
                                              ushort* __restrict__ W2f) {
    int idx = blockIdx.x * 256 + threadIdx.x;
    if (idx < 2048) {                        // W1f: 4 ct * 8 ks * 64 lanes
        int lane = idx & 63, ctks = idx >> 6;
        int ks = ctks & 7, ct = ctks >> 3;
        int col = ct * 16 + (lane & 15);
        int r0 = ks * 32 + (lane >> 4) * 8;
        bf16x8 frag;
        #pragma unroll
        for (int j = 0; j < 8; ++j) frag[j] = (short)f2bf(W1[(r0 + j) * NHID + col]);
        *(bf16x8*)&W1f[(size_t)idx * 8] = frag;
    } else if (idx < 2048 + 384) {           // W2f: 3 ct * 2 ks * 64 lanes
        int i2 = idx - 2048;
        int lane = i2 & 63, ctks = i2 >> 6;
        int ks = ctks & 1, ct = ctks >> 1;
        int col = ct * 16 + (lane & 15);
        int r0 = ks * 32 + (lane >> 4) * 8;
        bf16x8 frag;
        #pragma unroll
        for (int j = 0; j < 8; ++j)
            frag[j] = (short)((col < NCLASS) ? f2bf(W2[(r0 + j) * NCLASS + col]) : 0);
        *(bf16x8*)&W2f[(size_t)i2 * 8] = frag;
    }
}

// -------- mega: blocks 0..NBIN-1 = COARSE binning; rest = GEMM1 --------
__global__ __launch_bounds__(1024) void k_mega(const int* __restrict__ esrc,
                                               const int* __restrict__ edst,
                                               const float* __restrict__ ewt,
                                               int* __restrict__ bfillc,
                                               int2* __restrict__ coarse,
                                               const float* __restrict__ x,
                                               const ushort* __restrict__ W1f,
                                               ushort* __restrict__ xW1b) {
    __shared__ __align__(16) char smem[64 * 256 * 2];   // 32 KB
    int tid = threadIdx.x;

    if (blockIdx.x < NBIN) {
        // ---------------- coarse binning (full-line runs) ----------------
        int* cnt  = (int*)smem;              // [NC]
        int* base = cnt + NC;                // [NC]
        for (int i = tid; i < NC; i += 1024) cnt[i] = 0;
        __syncthreads();
        int eb = blockIdx.x * BIN_EPB;
        #pragma unroll
        for (int k = 0; k < BIN_EPB; k += 1024) {
            int e = eb + k + tid;
            if (e < N_EDGES) atomicAdd(&cnt[edst[e] >> 9], 1);
        }
        __syncthreads();
        for (int i = tid; i < NC; i += 1024) {
            int c = cnt[i];
            base[i] = c ? atomicAdd(&bfillc[i], c) : 0;
            cnt[i] = 0;
        }
        __syncthreads();
        #pragma unroll
        for (int k = 0; k < BIN_EPB; k += 1024) {
            int e = eb + k + tid;
            if (e < N_EDGES) {
                int d = edst[e];
                int c = d >> 9;
                int pos = base[c] + atomicAdd(&cnt[c], 1);
                coarse[(size_t)c * CAPC + pos] =
                    make_int2(esrc[e] | ((d & 511) << 16), __float_as_int(ewt[e]));
            }
        }
        return;
    }

    // ---------------- GEMM1 path: xW1b = bf16( x @ W1 ) ----------------
    ushort* sX = (ushort*)smem;              // 64 rows x 256 cols bf16
    int w = tid >> 6, lane = tid & 63;
    int ct = w & 3, rg = w >> 2;
    int row0 = (blockIdx.x - NBIN) * 64;

    bf16x8 Bf[8];
    #pragma unroll
    for (int ks = 0; ks < 8; ++ks)
        Bf[ks] = *(const bf16x8*)&W1f[(size_t)((ct * 8 + ks) * 64 + lane) * 8];

    {
        int row = tid & 63;
        int colbase = (tid >> 6) * 16;
        int crow = min(row0 + row, N_NODES - 1);
        const float* xp = x + (size_t)crow * NFEAT + colbase;
        #pragma unroll
        for (int c2 = 0; c2 < 2; ++c2) {
            float4 v0 = *(const float4*)(xp + c2 * 8);
            float4 v1 = *(const float4*)(xp + c2 * 8 + 4);
            bf16x8 fr;
            fr[0] = (short)f2bf(v0.x); fr[1] = (short)f2bf(v0.y);
            fr[2] = (short)f2bf(v0.z); fr[3] = (short)f2bf(v0.w);
            fr[4] = (short)f2bf(v1.x); fr[5] = (short)f2bf(v1.y);
            fr[6] = (short)f2bf(v1.z); fr[7] = (short)f2bf(v1.w);
            int chunk = colbase / 8 + c2;                 // 0..31
            *(bf16x8*)&sX[row * 256 + ((chunk ^ (row & 7)) * 8)] = fr;
        }
    }
    __syncthreads();

    f32x4 acc = {0.f, 0.f, 0.f, 0.f};
    int arow = rg * 16 + (lane & 15);
    #pragma unroll
    for (int ks = 0; ks < 8; ++ks) {
        int chunk = ks * 4 + (lane >> 4);
        bf16x8 Af = *(const bf16x8*)&sX[arow * 256 + ((chunk ^ (arow & 7)) * 8)];
        acc = __builtin_amdgcn_mfma_f32_16x16x32_bf16(Af, Bf[ks], acc, 0, 0, 0);
    }
    int col = ct * 16 + (lane & 15);
    int rbase = row0 + rg * 16 + (lane >> 4) * 4;
    #pragma unroll
    for (int r = 0; r < 4; ++r) {
        int row = rbase + r;
        if (row < N_NODES)
            xW1b[(size_t)row * NHID + col] = f2bf(acc[r]);
    }
}

// -------- pass B: coarse -> fine (32 buckets per coarse, full-line runs) --------
__global__ __launch_bounds__(512) void k_passB(const int* __restrict__ bfillc,
                                               const int2* __restrict__ coarse,
                                               int* __restrict__ bfill,
                                               int2* __restrict__ binned) {
    __shared__ int cnt[32];
    __shared__ int base[32];
    int tid = threadIdx.x;
    int c = blockIdx.x >> 1;
    int half = blockIdx.x & 1;
    int fillc = bfillc[c];
    int h0 = (fillc + 1) >> 1;
    int js = c * CAPC + half * h0;
    int je = c * CAPC + (half ? fillc : h0);

    if (tid < 32) cnt[tid] = 0;
    __syncthreads();
    for (int j = js + tid; j < je; j += 512) {
        int dstlow = (coarse[j].x >> 16) & 511;
        atomicAdd(&cnt[dstlow >> 4], 1);
    }
    __syncthreads();
    if (tid < 32) {
        int cc = cnt[tid];
        base[tid] = cc ? atomicAdd(&bfill[c * 32 + tid], cc) : 0;
        cnt[tid] = 0;
    }
    __syncthreads();
    for (int j = js + tid; j < je; j += 512) {
        int2 p = coarse[j];
        int dstlow = (p.x >> 16) & 511;
        int fb = dstlow >> 4;
        int pos = base[fb] + atomicAdd(&cnt[fb], 1);
        binned[(size_t)(c * 32 + fb) * CAP + pos] =
            make_int2((p.x & 0xFFFF) | ((dstlow & 15) << 16), p.y);
    }
}

// ---- SPMM1 + bias + ReLU + fused W2 projection: writes hW2b (16 x 48 bf16) ----
// 4 waves gather quarters into private slabs; reduce+bias+relu back into slab0;
// wave 0 projects 16x64 @ 64x48 with 6 MFMAs. h is never materialized globally.
__global__ __launch_bounds__(256) void k_spmm1b(const ushort* __restrict__ xW1b,
                                                const int* __restrict__ bfill,
                                                const int2* __restrict__ binned,
                                                const float* __restrict__ b1,
                                                const ushort* __restrict__ W2f,
                                                ushort* __restrict__ hW2b) {
    __shared__ float accs[4][NPB * ACC1S];   // 17 KB
    int wv = threadIdx.x >> 6, lane = threadIdx.x & 63;
    int b = blockIdx.x;
    float* acc = accs[wv];
    #pragma unroll
    for (int n = 0; n < NPB; ++n) acc[n * ACC1S + lane] = 0.f;

    int s = b * CAP, e = s + bfill[b];
    int len = e - s;
    int q = (len + 3) >> 2;
    int j = s + wv * q;
    int je = min(j + q, e);
    for (; j + 8 <= je; j += 8) {
        int2 p[8];
        #pragma unroll
        for (int k = 0; k < 8; ++k) p[k] = binned[j + k];
        float g[8];
        #pragma unroll
        for (int k = 0; k < 8; ++k)
            g[k] = bf2f(xW1b[(p[k].x & 0xFFFF) * NHID + lane]);
        #pragma unroll
        for (int k = 0; k < 8; ++k)
            acc[(p[k].x >> 16) * ACC1S + lane] += __int_as_float(p[k].y) * g[k];
    }
    for (; j < je; ++j) {
        int2 p0 = binned[j];
        float g0 = bf2f(xW1b[(p0.x & 0xFFFF) * NHID + lane]);
        acc[(p0.x >> 16) * ACC1S + lane] += __int_as_float(p0.y) * g0;
    }
    __syncthreads();

    // reduce 4 slabs -> slab0, + b1, ReLU (each (n,lane) touched by ONE thread)
    float bias = b1[lane];
    #pragma unroll
    for (int i = 0; i < 4; ++i) {
        int n = wv * 4 + i;
        int idx = n * ACC1S + lane;
        float v = accs[0][idx] + accs[1][idx] + accs[2][idx] + accs[3][idx] + bias;
        accs[0][idx] = v > 0.f ? v : 0.f;
    }
    __syncthreads();
    if (wv != 0) return;

    // wave 0: h tile (16x64) -> bf16 fragments -> 6 MFMAs -> hW2b
    bf16x8 Af[2];
    #pragma unroll
    for (int ks = 0; ks < 2; ++ks) {
        const float* ap = &accs[0][(lane & 15) * ACC1S + ks * 32 + (lane >> 4) * 8];
        #pragma unroll
        for (int jj = 0; jj < 8; ++jj) Af[ks][jj] = (short)f2bf(ap[jj]);
    }
    f32x4 cv[3] = {{0.f,0.f,0.f,0.f},{0.f,0.f,0.f,0.f},{0.f,0.f,0.f,0.f}};
    #pragma unroll
    for (int ct = 0; ct < 3; ++ct) {
        #pragma unroll
        for (int ks = 0; ks < 2; ++ks) {
            bf16x8 Bf = *(const bf16x8*)&W2f[(size_t)((ct * 2 + ks) * 64 + lane) * 8];
            cv[ct] = __builtin_amdgcn_mfma_f32_16x16x32_bf16(Af[ks], Bf, cv[ct], 0, 0, 0);
        }
    }
    int colg = lane & 15;
    int g = lane >> 4;
    #pragma unroll
    for (int i = 0; i < 4; ++i) {
        int node = b * NPB + g * 4 + i;
        ushort* o = hW2b + (size_t)node * NW2;
        o[colg]      = f2bf(cv[0][i]);
        o[16 + colg] = f2bf(cv[1][i]);
        o[32 + colg] = f2bf(cv[2][i]);
    }
}

// ------ SPMM2: gather hW2b (96B rows) + segment-sum + bias + log-softmax ------
__global__ __launch_bounds__(256) void k_spmm2g(const ushort* __restrict__ hW2b,
                                                const int* __restrict__ bfill,
                                                const int2* __restrict__ binned,
                                                const float* __restrict__ b2,
                                                float* __restrict__ out) {
    __shared__ float accs[4][NPB * 64];      // 16 KB
    int wv = threadIdx.x >> 6, lane = threadIdx.x & 63;
    int b = blockIdx.x;
    float* acc = accs[wv];
    int lf = lane < NW2 ? lane : 0;          // lanes 48..63 gather col 0 (benign)
    #pragma unroll
    for (int n = 0; n < NPB; ++n) acc[n * 64 + lane] = 0.f;

    int s = b * CAP, e = s + bfill[b];
    int len = e - s;
    int q = (len + 3) >> 2;
    int j = s + wv * q;
    int je = min(j + q, e);
    for (; j + 8 <= je; j += 8) {
        int2 p[8];
        #pragma unroll
        for (int k = 0; k < 8; ++k) p[k] = binned[j + k];
        float g[8];
        #pragma unroll
        for (int k = 0; k < 8; ++k)
            g[k] = bf2f(hW2b[(p[k].x & 0xFFFF) * NW2 + lf]);
        #pragma unroll
        for (int k = 0; k < 8; ++k)
            acc[(p[k].x >> 16) * 64 + lane] += __int_as_float(p[k].y) * g[k];
    }
    for (; j < je; ++j) {
        int2 p0 = binned[j];
        float g0 = bf2f(hW2b[(p0.x & 0xFFFF) * NW2 + lf]);
        acc[(p0.x >> 16) * 64 + lane] += __int_as_float(p0.y) * g0;
    }
    __syncthreads();

    float bias = (lane < NCLASS) ? b2[lane] : 0.f;
    #pragma unroll
    for (int i = 0; i < 4; ++i) {
        int n = wv * 4 + i;
        float vs = accs[0][n * 64 + lane] + accs[1][n * 64 + lane]
                 + accs[2][n * 64 + lane] + accs[3][n * 64 + lane];
        float v = (lane < NCLASS) ? (vs + bias) : -INFINITY;
        float m = v;
        #pragma unroll
        for (int off = 32; off; off >>= 1) m = fmaxf(m, __shfl_xor(m, off));
        float ex = (lane < NCLASS) ? __expf(v - m) : 0.f;
        float ssum = ex;
        #pragma unroll
        for (int off = 32; off; off >>= 1) ssum += __shfl_xor(ssum, off);
        float ls = __logf(ssum);
        if (lane < NCLASS) {
            int node = b * NPB + n;
            out[(size_t)node * NCLASS + lane] = v;
            out[(size_t)N_NODES * NCLASS + (size_t)node * NCLASS + lane] = v - m - ls;
        }
    }
}

// ---------------- launch ----------------

extern "C" void kernel_launch(void* const* d_in, const int* in_sizes, int n_in,
                              void* d_out, int out_size, void* d_ws, size_t ws_size,
                              hipStream_t stream) {
    const float* x    = (const float*)d_in[0];
    const float* W1   = (const float*)d_in[1];
    const float* b1   = (const float*)d_in[2];
    const float* W2   = (const float*)d_in[3];
    const float* b2   = (const float*)d_in[4];
    const float* ewt  = (const float*)d_in[5];
    const int*   esrc = (const int*)d_in[6];
    const int*   edst = (const int*)d_in[7];
    float* out = (float*)d_out;

    // workspace layout (16B-aligned chunks)
    char* p = (char*)d_ws;
    ushort* xW1b = (ushort*)p;   p += (size_t)N_NODES * NHID * 2;      // 6.40 MB
    ushort* hW2b = (ushort*)p;   p += (size_t)N_NODES * NW2 * 2;       // 4.80 MB
    int2*   binned = (int2*)p;   p += (size_t)NB * CAP * 8 + 64;       // 12.80 MB
    int2*   coarse = (int2*)p;   p += (size_t)NC * CAPC * 8;           // 12.85 MB
    ushort* W1f  = (ushort*)p;   p += 2048 * 8 * 2;                    // 32 KB
    ushort* W2f  = (ushort*)p;   p += 384 * 8 * 2;                     // 6 KB
    int* bfillc  = (int*)p;      p += NC * 4;                          // coarse fills
    int* bfill   = (int*)p;      p += NB * 4;                          // fine fills

    hipMemsetAsync(bfillc, 0, (NC + NB) * sizeof(int), stream);

    k_prep<<<10, 256, 0, stream>>>(W1, W2, W1f, W2f);
    k_mega<<<NBIN + NGEMM, 1024, 0, stream>>>(esrc, edst, ewt, bfillc, coarse,
                                              x, W1f, xW1b);
    k_passB<<<NC * 2, 512, 0, stream>>>(bfillc, coarse, bfill, binned);
    k_spmm1b<<<NB, 256, 0, stream>>>(xW1b, bfill, binned, b1, W2f, hW2b);
    k_spmm2g<<<NB, 256, 0, stream>>>(hW2b, bfill, binned, b2, out);
}